// Round 16
// baseline (469.273 us; speedup 1.0000x reference)
//
#include <hip/hip_runtime.h>
#include <hip/hip_bf16.h>

constexpr int B  = 16;
constexpr int C  = 128;
constexpr int H  = 128;
constexpr int W  = 128;
constexpr int CO = 256;
constexpr int HO = 64;
constexpr int WO = 64;

#define EPSV   1e-8f
#define SLOPE  0.2f

typedef short bf16x8 __attribute__((ext_vector_type(8)));
typedef float f32x4  __attribute__((ext_vector_type(4)));

__device__ __forceinline__ short f2bs(float v) {
    __hip_bfloat16 h = __float2bfloat16(v);
    return *(short*)&h;
}
__device__ __forceinline__ float bs2f(short s) {
    __hip_bfloat16 h = *(__hip_bfloat16*)&s;
    return __bfloat162float(h);
}

// ---------------------------------------------------------------------------
// prep mega-kernel (r16): ONE launch for all pre-MFMA work.
//   blocks    0-2047 : nchw(f32) -> nhwc(bf16) transpose
//   blocks 2048-4095 : dwexpand
//   blocks 4096-8191 : FUSED demod+expand — one block per (cb, oc).
//     phase 1: coalesced read of w[oc,:,:] (1152 f32), block-reduce ->
//              d = rsqrt(sum((w*(s+1))^2)+eps)  (demod inlined; kills the
//              dv dependency that forced expand into a separate launch)
//     phase 2: 144 threads re-gather the L1-hot w values, scale, pack,
//              16B uint4 stores into wm.
// r14 LESSON kept: transpose stays a dedicated float4/uint4 section.
// Saves: 1 launch gap + demod's separate pass over w1/w2.
// ---------------------------------------------------------------------------
__global__ __launch_bounds__(256) void prep_kernel(
    const float* __restrict__ in, short* __restrict__ outNhwc,
    const float* __restrict__ dw, short* __restrict__ dwm,
    const float* __restrict__ w1, const float* __restrict__ w2,
    const float* __restrict__ s1, const float* __restrict__ s2,
    short* __restrict__ wm)
{
    __shared__ short s[128 * 136];
    int gb  = blockIdx.x;
    int tid = threadIdx.x;

    if (gb < 2048) {
        // ---- nchw(f32) -> nhwc(bf16) transpose ----
        int h = gb & 127, b = gb >> 7;
        for (int i = tid; i < 128 * 32; i += 256) {
            int w4 = i & 31, ic = i >> 5;
            float4 v = *(const float4*)&in[((b * C + ic) * H + h) * W + w4 * 4];
            s[(w4 * 4 + 0) * 136 + ic] = f2bs(v.x);
            s[(w4 * 4 + 1) * 136 + ic] = f2bs(v.y);
            s[(w4 * 4 + 2) * 136 + ic] = f2bs(v.z);
            s[(w4 * 4 + 3) * 136 + ic] = f2bs(v.w);
        }
        __syncthreads();
        for (int i = tid; i < 128 * 16; i += 256) {
            int icg = i & 15, w = i >> 4;
            *(uint4*)&outNhwc[((b * H + h) * W + w) * C + icg * 8] =
                *(uint4*)&s[w * 136 + icg * 8];
        }
    } else if (gb < 4096) {
        // ---- dwexpand: dwm[tap][ocT][icC][(oc&15)*32+(ic&31)] ----
        int idx = (gb - 2048) * 256 + tid;
        int ic  = idx & 127;
        int oc  = (idx >> 7) & 255;
        int tap = idx >> 15;
        int dst = ((tap * 16 + (oc >> 4)) * 4 + (ic >> 5)) * 512
                + (oc & 15) * 32 + (ic & 31);
        dwm[dst] = f2bs(dw[(oc * C + ic) * 16 + tap]);
    } else {
        // ---- fused demod+expand: block = (cb, oc) ----
        int x    = gb - 4096;          // 0..4095
        int oc   = x & 127;
        int cb   = x >> 7;             // conv*16 + b
        int b    = cb & 15;
        int conv = cb >> 4;
        const float* w  = conv ? w2 : w1;
        const float* sv = conv ? s2 : s1;

        // phase 1: sum over 1152 elems; j = ic*9 + k -> w reads coalesced
        float sum = 0.f;
        for (int j = tid; j < 1152; j += 256) {
            int ic   = j / 9;
            float wv = w[oc * 1152 + j];
            float sc = sv[b * C + ic] + 1.0f;
            float t  = wv * sc;
            sum += t * t;
        }
        #pragma unroll
        for (int off = 32; off; off >>= 1) sum += __shfl_down(sum, off);
        __shared__ float red[4];
        if ((tid & 63) == 0) red[tid >> 6] = sum;
        __syncthreads();
        float dval = rsqrtf(red[0] + red[1] + red[2] + red[3] + EPSV);

        // phase 2: 144 items = 9 taps x 16 ic-octets; w re-reads are L1-hot
        if (tid < 144) {
            int tap = tid / 16;
            int ico = tid & 15;
            int ic0 = ico * 8;
            short vs[8];
            #pragma unroll
            for (int i = 0; i < 8; ++i) {
                float wv = w[(oc * C + ic0 + i) * 9 + tap];
                float sc = sv[b * C + ic0 + i] + 1.0f;
                vs[i] = f2bs(wv * sc * dval);
            }
            int dst = cb * 147456
                    + ((tap * 8 + (oc >> 4)) * 4 + (ic0 >> 5)) * 512
                    + (oc & 15) * 32 + (ic0 & 31);
            *(uint4*)&wm[dst] = *(uint4*)vs;
        }
    }
}

// ---------------------------------------------------------------------------
// conv3x3 MFMA implicit GEMM — r11 configuration (counter-verified best:
// ~106 us, MfmaUtil 31%, VGPR 80). r9 retile (wave = 128px x 32oc,
// dedup'd weight loads) + r11 SALU addressing + T5 setprio + T1 swizzle.
// FROZEN.  LESSONS (do not regress):
//  r5/r12: bf prefetch distance 2 null/REGRESS at BOTH tilings.
//  r7: per-step barrier pipeline REGRESS (36 vmcnt(0) drains unamortized).
//  r14: NCHW staging fusion REGRESS (scalar LDS stores, 222us).
//  r9: retile WIN (-22%); r11: SALU addressing ~+4%.
// ---------------------------------------------------------------------------
__global__ __launch_bounds__(256, 3) void conv3x3_mfma(
    const short* __restrict__ in, const short* __restrict__ wmc,
    const short* __restrict__ res, short* __restrict__ out)
{
    __shared__ short sIn[10 * 18 * 136];   // 48,960 B

    // T1: XCD-aware swizzle (r6: weights L2-resident per XCD; keep).
    int bid0 = blockIdx.x;
    int bid  = (bid0 & 7) * 256 + (bid0 >> 3);

    int wt = bid & 7, ht = (bid >> 3) & 15, b = bid >> 7;
    int w0 = wt * 16, h0 = ht * 8;
    int tid  = threadIdx.x;
    int lane = tid & 63;
    int wv   = __builtin_amdgcn_readfirstlane(tid >> 6);   // SGPR wave idx
    int q = lane >> 4, l15 = lane & 15;

    for (int i = tid; i < 10 * 18 * 16; i += 256) {
        int icg = i & 15;
        int t = i >> 4;
        int wl = t % 18, hl = t / 18;
        int gh = h0 - 1 + hl, gw = w0 - 1 + wl;
        uint4 v = make_uint4(0u, 0u, 0u, 0u);
        if ((unsigned)gh < (unsigned)H && (unsigned)gw < (unsigned)W)
            v = *(const uint4*)&in[((b * H + gh) * W + gw) * C + icg * 8];
        *(uint4*)&sIn[(hl * 18 + wl) * 136 + icg * 8] = v;
    }
    __syncthreads();

    // SGPR base for this wave's weight frags; VGPR lane offset hoisted once.
    const short* wbW = wmc + b * 147456 + wv * 4096;   // (wv*2 frags)*4c*512
    int bfLane = l15 * 32 + q * 8;                      // invariant VGPR
    const short* afB = sIn + l15 * 136 + q * 8;         // invariant LDS base

    f32x4 acc[8][2];
    #pragma unroll
    for (int mt = 0; mt < 8; ++mt)
        #pragma unroll
        for (int nt = 0; nt < 2; ++nt)
            acc[mt][nt] = (f32x4){0.f, 0.f, 0.f, 0.f};

    bf16x8 af[2][8];   // pixels (LDS), parity s&1, distance 1; 8 h-rows
    bf16x8 bf[2][2];   // weights (global), parity s&1, distance 1; 2 oc-tiles

    // K-step s = tap*4 + c  (tap = s>>2, c = s&3)
    auto ldAF = [&](int slot, int tap, int c) {
        int dh = tap / 3, dw = tap - dh * 3;
        #pragma unroll
        for (int mt = 0; mt < 8; ++mt)
            af[slot][mt] = *(const bf16x8*)(afB + (dh * 18 + dw) * 136 + c * 32
                                            + mt * 2448);
    };
    auto ldBF = [&](int slot, int tap, int c) {
        #pragma unroll
        for (int nt = 0; nt < 2; ++nt)
            bf[slot][nt] = *(const bf16x8*)(wbW + ((tap * 8 + nt) * 4 + c) * 512
                                            + bfLane);
    };

    // prologue: step 0 operands
    ldAF(0, 0, 0);
    ldBF(0, 0, 0);

    #pragma unroll
    for (int s = 0; s < 36; ++s) {
        // prefetch step s+1 (global first: longer latency)
        int s1 = (s + 1 < 36) ? s + 1 : s;       // dummy at tail
        ldBF((s + 1) & 1, s1 >> 2, s1 & 3);
        ldAF((s + 1) & 1, s1 >> 2, s1 & 3);
        // compute step s (T5)
        __builtin_amdgcn_s_setprio(1);
        #pragma unroll
        for (int mt = 0; mt < 8; ++mt)
            #pragma unroll
            for (int nt = 0; nt < 2; ++nt)
                acc[mt][nt] = __builtin_amdgcn_mfma_f32_16x16x32_bf16(
                    af[s & 1][mt], bf[s & 1][nt], acc[mt][nt], 0, 0, 0);
        __builtin_amdgcn_s_setprio(0);
    }

    bool has_res = (res != nullptr);
    #pragma unroll
    for (int mt = 0; mt < 8; ++mt) {
        int h = h0 + mt;
        #pragma unroll
        for (int nt = 0; nt < 2; ++nt) {
            int oc = wv * 32 + nt * 16 + l15;
            #pragma unroll
            for (int reg = 0; reg < 4; ++reg) {
                int w = w0 + q * 4 + reg;
                int idx = ((b * H + h) * W + w) * C + oc;
                float v = acc[mt][nt][reg];
                if (has_res) v += bs2f(res[idx]);
                v = v >= 0.f ? v : SLOPE * v;
                out[idx] = f2bs(v);
            }
        }
    }
}

// ---------------------------------------------------------------------------
// downconv MFMA — r10 retile + r11 SALU addressing. FROZEN.
// LESSONS: r1 spill, r3 restructure regress, r4 setprio WIN, r10 retile WIN.
// ---------------------------------------------------------------------------
__global__ __launch_bounds__(256, 2) void downconv_mfma(
    const short* __restrict__ in, const short* __restrict__ dwm,
    const float* __restrict__ db, float* __restrict__ out)
{
    __shared__ short sIn[19 * 2 * 18 * 40];   // 54,720 B

    int bid = blockIdx.x;
    int wt = bid & 3;  bid >>= 2;
    int ht = bid & 7;  bid >>= 3;
    int ot = bid & 1;  bid >>= 1;
    int b  = bid;
    int ow0 = wt * 16, oh0 = ht * 8, oc0 = ot * 128;

    int tid  = threadIdx.x;
    int lane = tid & 63;
    int wv   = __builtin_amdgcn_readfirstlane(tid >> 6);
    int q = lane >> 4, l15 = lane & 15;

    f32x4 acc[2][8];
    #pragma unroll
    for (int mt = 0; mt < 2; ++mt)
        #pragma unroll
        for (int nt = 0; nt < 8; ++nt)
            acc[mt][nt] = (f32x4){0.f, 0.f, 0.f, 0.f};

    int ocTb = ot * 8 + wv * 2;

    for (int i = tid; i < 19 * 35 * 4; i += 256) {
        int icg = i & 3;
        int t = i >> 2;
        int wl = t % 35, hl = t / 35;
        int gh = 2 * oh0 - 1 + hl, gw = 2 * ow0 - 1 + wl;
        uint4 v = make_uint4(0u, 0u, 0u, 0u);
        if ((unsigned)gh < (unsigned)H && (unsigned)gw < (unsigned)W)
            v = *(const uint4*)&in[((b * H + gh) * W + gw) * C + icg * 8];
        *(uint4*)&sIn[((hl * 2 + (wl & 1)) * 18 + (wl >> 1)) * 40 + icg * 8] = v;
    }

    const short* dwW = dwm + ocTb * 2048;
    int dwLane = l15 * 32 + q * 8;
    const short* bfB = sIn + l15 * 40 + q * 8;

    bf16x8 af[4][2];
    bf16x8 bf[2][8];

    #pragma unroll
    for (int s = 0; s < 3; ++s)
        #pragma unroll
        for (int mt = 0; mt < 2; ++mt)
            af[s][mt] = *(const bf16x8*)(dwW + (s * 16 + mt) * 2048 + dwLane);

    __syncthreads();

    #pragma unroll 1
    for (int c = 0; c < 4; ++c) {
        #pragma unroll
        for (int nt = 0; nt < 8; ++nt)
            bf[0][nt] = *(const bf16x8*)(bfB + (2 * nt) * 2 * 18 * 40);

        #pragma unroll
        for (int tap = 0; tap < 16; ++tap) {
            {
                int sp = c * 16 + tap + 3;
                sp = sp < 63 ? sp : 63;
                int pc = sp >> 4, pt = sp & 15;
                #pragma unroll
                for (int mt = 0; mt < 2; ++mt)
                    af[(tap + 3) & 3][mt] =
                        *(const bf16x8*)(dwW + (pt * 16 + mt) * 2048 + pc * 512
                                         + dwLane);
            }
            {
                int tapn = (tap + 1 < 16) ? tap + 1 : tap;
                int dhn = tapn >> 2, dwn = tapn & 3;
                #pragma unroll
                for (int nt = 0; nt < 8; ++nt) {
                    int hl = 2 * nt + dhn;
                    bf[(tap + 1) & 1][nt] =
                        *(const bf16x8*)(bfB + ((hl * 2 + (dwn & 1)) * 18
                                                + (dwn >> 1)) * 40);
                }
            }
            __builtin_amdgcn_s_setprio(1);
            #pragma unroll
            for (int mt = 0; mt < 2; ++mt)
                #pragma unroll
                for (int nt = 0; nt < 8; ++nt)
                    acc[mt][nt] = __builtin_amdgcn_mfma_f32_16x16x32_bf16(
                        af[tap & 3][mt], bf[tap & 1][nt], acc[mt][nt], 0, 0, 0);
            __builtin_amdgcn_s_setprio(0);
        }

        if (c < 3) {
            __syncthreads();
            for (int i = tid; i < 19 * 35 * 4; i += 256) {
                int icg = i & 3;
                int t = i >> 2;
                int wl = t % 35, hl = t / 35;
                int gh = 2 * oh0 - 1 + hl, gw = 2 * ow0 - 1 + wl;
                uint4 v = make_uint4(0u, 0u, 0u, 0u);
                if ((unsigned)gh < (unsigned)H && (unsigned)gw < (unsigned)W)
                    v = *(const uint4*)&in[((b * H + gh) * W + gw) * C
                                           + (c + 1) * 32 + icg * 8];
                *(uint4*)&sIn[((hl * 2 + (wl & 1)) * 18 + (wl >> 1)) * 40 + icg * 8] = v;
            }
            __syncthreads();
        }
    }

    #pragma unroll
    for (int mt = 0; mt < 2; ++mt) {
        #pragma unroll
        for (int reg = 0; reg < 4; ++reg) {
            int oc = oc0 + wv * 32 + mt * 16 + q * 4 + reg;
            float bias = db[oc];
            #pragma unroll
            for (int nt = 0; nt < 8; ++nt) {
                int oh = oh0 + nt;
                int ow = ow0 + l15;
                out[((b * CO + oc) * HO + oh) * WO + ow] = acc[mt][nt][reg] + bias;
            }
        }
    }
}

// ---------------------------------------------------------------------------
extern "C" void kernel_launch(void* const* d_in, const int* in_sizes, int n_in,
                              void* d_out, int out_size, void* d_ws, size_t ws_size,
                              hipStream_t stream) {
    const float* features = (const float*)d_in[0];
    const float* sm1      = (const float*)d_in[1];   // style_mean1 -> s1
    const float* ss1      = (const float*)d_in[2];   // style_std1  -> s2 (per reference)
    const float* w1       = (const float*)d_in[6];
    const float* w2       = (const float*)d_in[7];
    const float* dw       = (const float*)d_in[8];
    const float* db       = (const float*)d_in[9];
    float* out = (float*)d_out;

    char* ws = (char*)d_ws;
    short* x1  = (short*)ws;                              // 67,108,864 B
    short* x2  = (short*)(ws + 67108864);                 // 67,108,864 B
    short* wm  = (short*)(ws + 134217728);                // 9,437,184 B
    short* dwm = (short*)(ws + 143654912);                // 1,048,576 B

    // prep: transpose (0-2047) + dwexpand (2048-4095)
    //       + fused demod-expand (4096-8191)   — 4 launches total now.
    prep_kernel   <<<8192, 256, 0, stream>>>(features, x2, dw, dwm,
                                             w1, w2, sm1, ss1, wm);
    conv3x3_mfma  <<<2048, 256, 0, stream>>>(x2, wm, nullptr, x1);
    conv3x3_mfma  <<<2048, 256, 0, stream>>>(x1, wm + 16 * 147456, x1, x2);
    downconv_mfma <<<1024, 256, 0, stream>>>(x2, dwm, db, out);
}